// Round 1
// 825.225 us; speedup vs baseline: 1.0415x; 1.0415x over previous
//
#include <hip/hip_runtime.h>
#include <hip/hip_bf16.h>

// WindowAttention: B=2048 windows, N=98 tokens, C=192, H=6 heads, hd=32, nw=64 masks.
// K0 prep (x->f16 bulk convert into d_out scratch, o_w/qkv_w->f16, bias gather);
// K1 QKV GEMM: A staged via async global_load_lds (width=16) into linear 48KB LDS with
//   XOR source-swizzle (row&7)<<4 for conflict-free ds_read_b128 fragments; B direct-global
//   f16 from L2; 128x64 tile, XCD swizzle. K2 per-(b,h) attention (448 thr, K in LDS,
//   register softmax); K3 out-proj (32x32 tile/wave, XCD swizzle).
// ws usage identical (308.6 MB); xh (f16 x copy, 77,070,336 B) lives in d_out and is
// fully overwritten by K3. f16 qkv_w copy aliased into the ao region as before.

#define NB   2048
#define NN   98
#define CC   192
#define NH   6
#define HD   32
#define NWIN 64
#define MM   (NB * NN)          // 200704 rows
#define HEADBLK (NN * HD)       // 3136 elements per (b,s,h) slice

typedef _Float16 half8  __attribute__((ext_vector_type(8)));
typedef float    f32x4  __attribute__((ext_vector_type(4)));

__device__ __forceinline__ f32x4 mfma16(half8 a, half8 b, f32x4 c) {
    return __builtin_amdgcn_mfma_f32_16x16x32_f16(a, b, c, 0, 0, 0);
}

typedef __attribute__((address_space(3))) unsigned int       lds_uint;
typedef __attribute__((address_space(1))) const unsigned int g_uint;
__device__ __forceinline__ void async_copy16(void* lds, const void* g) {
    // 16B direct global->LDS DMA; LDS dest = wave-uniform base + lane*16
    __builtin_amdgcn_global_load_lds((g_uint*)g, (lds_uint*)lds, 16, 0, 0);
}

// ---------------- workspace layout (bytes) ----------------
// qkv f16   : [2048][3][6][98][32]            231,211,008 B @ 0
// attn_out  : [200704][192] f16                77,070,336 B @ 231,211,008
//   (first 221,184 B alias the f16 qkv_w copy: K0 writes, K1 reads, K2 overwrites)
// o_w f16   : [192][192]                           73,728 B @ 308,281,344
// bias_pre  : [6][98][98] f32                     230,496 B @ 308,355,072   (total 308,585,568)
// xh f16    : [200704][192]                    77,070,336 B in d_out (K0 writes, K1 reads, K3 overwrites)
#define WS_QKV   0ull
#define WS_AO    231211008ull
#define WS_W2    308281344ull
#define WS_BIAS  308355072ull

// ---------------- K0: prep (x->f16, o_w->f16, qkv_w->f16, bias gather) ----------------
__global__ __launch_bounds__(256) void wa_k0_prep(
    const float* __restrict__ x,
    const float* __restrict__ o_w, const float* __restrict__ qkv_w,
    const float* __restrict__ bias_table, const int* __restrict__ rel_index,
    _Float16* __restrict__ w2, _Float16* __restrict__ wqh,
    float* __restrict__ bias_pre, _Float16* __restrict__ xh)
{
    int t = blockIdx.x * 256 + threadIdx.x;
    if (t < CC * CC) {
        w2[t] = (_Float16)o_w[t];
    } else if (t < CC * CC + 3 * CC * CC) {
        int e = t - CC * CC;
        wqh[e] = (_Float16)qkv_w[e];
    } else if (t < CC * CC + 3 * CC * CC + NH * NN * NN) {
        int e = t - 4 * CC * CC;        // e = h*9604 + r
        int h = e / (NN * NN);
        int r = e - h * (NN * NN);
        bias_pre[e] = bias_table[rel_index[r] * NH + h];
    }
    // bulk x (f32) -> xh (f16): 38,535,168 elems = 4,816,896 granules of 8
    const size_t total_g = (size_t)MM * CC / 8;
    const size_t stride  = (size_t)gridDim.x * 256;
    for (size_t g = t; g < total_g; g += stride) {
        const float* s = x + g * 8;
        float4 v0 = *(const float4*)s;
        float4 v1 = *(const float4*)(s + 4);
        half8 hv = { (_Float16)v0.x, (_Float16)v0.y, (_Float16)v0.z, (_Float16)v0.w,
                     (_Float16)v1.x, (_Float16)v1.y, (_Float16)v1.z, (_Float16)v1.w };
        *(half8*)(xh + g * 8) = hv;
    }
}

// ---------------- K1: QKV projection GEMM ----------------
// 128x64 output tile per block; A (xh rows, f16) staged async into linear LDS [128][192]
// with XOR source-swizzle; B fragments direct from f16 qkv_w copy (L2-resident).
// grid = 14112 linear, XCD-swizzled so one mb's 9 n-blocks share an XCD.
__global__ __launch_bounds__(256) void wa_k1_qkv(
    const _Float16* __restrict__ xh, const _Float16* __restrict__ wqh,
    const float* __restrict__ qkv_b, _Float16* __restrict__ qkv)
{
    const int id = blockIdx.x;                 // 0..14111 = 8*9*196
    const int c8 = id & 7;
    const int nb = (id >> 3) % 9;              // 0..8
    const int mb = (id / 72) * 8 + c8;         // 0..1567
    __shared__ __align__(128) _Float16 As[128 * 192];   // 48 KB, linear rows of 384 B

    const int tid  = threadIdx.x;
    const int lane = tid & 63, wave = tid >> 6;

    // ---- async stage: 48 KB = 12 rounds x 4 waves x 64 lanes x 16 B ----
    // LDS is linear; the XOR swizzle (row&7)<<4 is applied to the GLOBAL source address
    // (involution), and again on the LDS read side below.
    {
        const char* xb = (const char*)(xh + (size_t)mb * 128 * CC);
        char* lb = (char*)As + wave * 1024;
        #pragma unroll
        for (int i = 0; i < 12; ++i) {
            int off = i * 4096 + wave * 1024 + lane * 16;   // dest byte offset
            int row = off / 384;
            int col = off - row * 384;
            int src = row * 384 + (col ^ ((row & 7) << 4));
            async_copy16(lb + i * 4096, xb + src);
        }
    }

    const int l16 = lane & 15, quad = lane >> 4;
    const _Float16* bbase = wqh + (size_t)(nb * 64 + l16) * CC + quad * 8;

    // prefetch kk=0 B fragments before the barrier (independent of LDS)
    half8 b0[4];
    #pragma unroll
    for (int nt = 0; nt < 4; ++nt) b0[nt] = *(const half8*)(bbase + nt * 16 * CC);

    __syncthreads();   // drains vmcnt -> staged tile visible

    const char* asb = (const char*)As;
    const int sx = (l16 & 7) << 4;                   // (row&7)<<4, rows differ by 16
    const int r0 = (wave * 32 + l16) * 384;          // byte row base, a0
    const int r1 = r0 + 16 * 384;                    // a1
    const int cb = quad * 16;                        // byte col base

    f32x4 acc[2][4] = {};
    #pragma unroll
    for (int kk = 0; kk < 6; ++kk) {
        int c = (cb + kk * 64) ^ sx;
        half8 a0 = *(const half8*)(asb + r0 + c);
        half8 a1 = *(const half8*)(asb + r1 + c);
        #pragma unroll
        for (int nt = 0; nt < 4; ++nt) {
            half8 b = (kk == 0) ? b0[nt]
                                : *(const half8*)(bbase + nt * 16 * CC + kk * 32);
            acc[0][nt] = mfma16(a0, b, acc[0][nt]);
            acc[1][nt] = mfma16(a1, b, acc[1][nt]);
        }
    }

    // epilogue: + qkv_b, scatter f16 to [b][s][h][i][d]
    int bArr[8], iArr[8];
    #pragma unroll
    for (int mi = 0; mi < 2; ++mi)
        #pragma unroll
        for (int r = 0; r < 4; ++r) {
            int m = mb * 128 + wave * 32 + mi * 16 + quad * 4 + r;
            int b_ = m / NN;
            bArr[mi * 4 + r] = b_;
            iArr[mi * 4 + r] = m - b_ * NN;
        }
    #pragma unroll
    for (int nt = 0; nt < 4; ++nt) {
        int j = nb * 64 + nt * 16 + l16;        // 0..575
        float bias = qkv_b[j];
        int s  = j / CC;
        int rm = j - s * CC;
        int h  = rm >> 5;
        int d  = rm & 31;
        #pragma unroll
        for (int mi = 0; mi < 2; ++mi)
            #pragma unroll
            for (int r = 0; r < 4; ++r) {
                int e = mi * 4 + r;
                qkv[((size_t)(bArr[e] * 3 + s) * NH + h) * HEADBLK + iArr[e] * HD + d] =
                    (_Float16)(acc[mi][nt][r] + bias);
            }
    }
}

// ---------------- K2: attention per (b,h), 448 threads = 7 waves ----------------
__global__ __launch_bounds__(448) void wa_k2_attn(
    const _Float16* __restrict__ qkv, const float* __restrict__ mask,
    const float* __restrict__ bias_pre, _Float16* __restrict__ ao)
{
    const int h = blockIdx.x;           // 0..5
    const int b = blockIdx.y;           // 0..2047
    const int widx = b & (NWIN - 1);
    const _Float16* qp = qkv + ((size_t)(b * 3 + 0) * NH + h) * HEADBLK;
    const _Float16* kp = qkv + ((size_t)(b * 3 + 1) * NH + h) * HEADBLK;
    const _Float16* vp = qkv + ((size_t)(b * 3 + 2) * NH + h) * HEADBLK;

    __shared__ __align__(16) _Float16 Kl[112 * 40];   // K rows, stride 40 (conflict-free frag reads)
    __shared__ __align__(16) _Float16 Vt[32 * 136];   // V transposed [d][j], j-pad to 128
    __shared__ __align__(16) _Float16 P[112 * 136];   // probs, K-pad to 128

    const int tid = threadIdx.x;
    // stage K: 392 granules of 8 f16, one shot
    if (tid < 392) {
        int row = tid >> 2, g = tid & 3;
        *(half8*)(Kl + row * 40 + g * 8) = *(const half8*)(kp + row * 32 + g * 8);
    }
    // zero K pad rows 98..111 (560 f16 = 280 dwords, contiguous)
    if (tid < 280) ((unsigned int*)Kl)[1960 + tid] = 0u;
    // stage V transposed (3136 = 448*7)
    for (int idx = tid; idx < NN * HD; idx += 448) {
        int j = idx >> 5, d = idx & 31;
        Vt[d * 136 + j] = vp[idx];
    }
    // zero Vt cols 98..135
    for (int idx = tid; idx < 32 * 38; idx += 448) {
        int d = idx / 38;
        Vt[d * 136 + NN + (idx - d * 38)] = (_Float16)0.f;
    }
    // zero P cols 112..127 (read by PV, never written by softmax)
    for (int idx = tid; idx < 896; idx += 448) {
        int row = idx >> 3;
        ((unsigned int*)P)[row * 68 + 56 + (idx & 7)] = 0u;
    }
    __syncthreads();

    const int lane = tid & 63, wave = tid >> 6;
    const int l16 = lane & 15, quad = lane >> 4;
    const float scale = 0.17677669529663687f;   // 32^-0.5

    // ---- S = QK^T (one m-tile per wave), register softmax, write P ----
    {
        const int mt = wave;                    // 0..6
        int ia = mt * 16 + l16;
        int ic = ia < NN ? ia : NN - 1;         // clamp pad rows
        half8 aq = *(const half8*)(qp + ic * HD + quad * 8);

        f32x4 s[7];
        #pragma unroll
        for (int jt = 0; jt < 7; ++jt) {
            half8 bk = *(const half8*)(Kl + (jt * 16 + l16) * 40 + quad * 8);
            f32x4 z = {};
            s[jt] = mfma16(aq, bk, z);
        }

        const int irow_base = mt * 16 + quad * 4;
        #pragma unroll
        for (int r = 0; r < 4; ++r) {
            int ir  = irow_base + r;
            int irc = ir < NN ? ir : NN - 1;
            const float* bp = bias_pre + (h * NN + irc) * NN;
            const float* mp = mask + ((size_t)widx * NN + irc) * NN;
            #pragma unroll
            for (int jt = 0; jt < 7; ++jt) {
                int jcol = jt * 16 + l16;
                s[jt][r] = (jcol < NN)
                    ? fmaf(s[jt][r], scale, bp[jcol] + mp[jcol])
                    : -__builtin_inff();
            }
        }

        #pragma unroll
        for (int r = 0; r < 4; ++r) {
            float mx = -__builtin_inff();
            #pragma unroll
            for (int jt = 0; jt < 7; ++jt) mx = fmaxf(mx, s[jt][r]);
            mx = fmaxf(mx, __shfl_xor(mx, 1));
            mx = fmaxf(mx, __shfl_xor(mx, 2));
            mx = fmaxf(mx, __shfl_xor(mx, 4));
            mx = fmaxf(mx, __shfl_xor(mx, 8));
            float sum = 0.f;
            #pragma unroll
            for (int jt = 0; jt < 7; ++jt) {
                float p = __expf(s[jt][r] - mx);
                s[jt][r] = p;
                sum += p;
            }
            sum += __shfl_xor(sum, 1);
            sum += __shfl_xor(sum, 2);
            sum += __shfl_xor(sum, 4);
            sum += __shfl_xor(sum, 8);
            float inv = 1.0f / sum;
            int prow = irow_base + r;
            #pragma unroll
            for (int jt = 0; jt < 7; ++jt)
                P[prow * 136 + jt * 16 + l16] = (_Float16)(s[jt][r] * inv);
        }
    }
    __syncthreads();

    // ---- O = P @ V : 14 tiles over 7 waves, K = 128 (zero-padded) ----
    #pragma unroll
    for (int ti = 0; ti < 2; ++ti) {
        int t = wave * 2 + ti;
        int mt = t >> 1, nt = t & 1;
        f32x4 acc = {};
        #pragma unroll
        for (int kc = 0; kc < 4; ++kc) {
            half8 a = *(const half8*)(P  + (mt * 16 + l16) * 136 + kc * 32 + quad * 8);
            half8 b = *(const half8*)(Vt + (nt * 16 + l16) * 136 + kc * 32 + quad * 8);
            acc = mfma16(a, b, acc);
        }
        #pragma unroll
        for (int r = 0; r < 4; ++r) {
            int i = mt * 16 + quad * 4 + r;
            if (i < NN) {
                int d = nt * 16 + l16;
                ao[((size_t)b * NN + i) * CC + h * HD + d] = (_Float16)acc[r];
            }
        }
    }
}

// ---------------- K3: output projection, 32x32 tile per wave ----------------
__global__ __launch_bounds__(256) void wa_k3_proj(
    const _Float16* __restrict__ ao, const _Float16* __restrict__ w2,
    const float* __restrict__ o_b, float* __restrict__ out)
{
    const int id = blockIdx.x;                 // 0..9407 = 8*6*196
    const int c8 = id & 7;
    const int nt = (id >> 3) % 6;
    const int msuper = (id / 48) * 8 + c8;     // 0..1567
    const int lane = threadIdx.x & 63, wave = threadIdx.x >> 6;
    const int l16 = lane & 15, quad = lane >> 4;

    const int m0 = msuper * 128 + wave * 32;
    const int e0 = nt * 32;
    const _Float16* ap = ao + (size_t)(m0 + l16) * CC + quad * 8;
    const _Float16* bp = w2 + (size_t)(e0 + l16) * CC + quad * 8;

    f32x4 acc[2][2] = {};
    #pragma unroll
    for (int kk = 0; kk < 6; ++kk) {
        half8 a0 = *(const half8*)(ap + kk * 32);
        half8 a1 = *(const half8*)(ap + 16 * CC + kk * 32);
        half8 b0 = *(const half8*)(bp + kk * 32);
        half8 b1 = *(const half8*)(bp + 16 * CC + kk * 32);
        acc[0][0] = mfma16(a0, b0, acc[0][0]);
        acc[0][1] = mfma16(a0, b1, acc[0][1]);
        acc[1][0] = mfma16(a1, b0, acc[1][0]);
        acc[1][1] = mfma16(a1, b1, acc[1][1]);
    }
    #pragma unroll
    for (int ni = 0; ni < 2; ++ni) {
        int e = e0 + ni * 16 + l16;
        float ob = o_b[e];
        #pragma unroll
        for (int mi = 0; mi < 2; ++mi)
            #pragma unroll
            for (int r = 0; r < 4; ++r) {
                int m = m0 + mi * 16 + quad * 4 + r;
                out[(size_t)m * CC + e] = acc[mi][ni][r] + ob;
            }
    }
}

// ---------------- launcher ----------------
extern "C" void kernel_launch(void* const* d_in, const int* in_sizes, int n_in,
                              void* d_out, int out_size, void* d_ws, size_t ws_size,
                              hipStream_t stream)
{
    const float* x          = (const float*)d_in[0];
    const float* mask       = (const float*)d_in[1];
    const float* qkv_w      = (const float*)d_in[2];
    const float* qkv_b      = (const float*)d_in[3];
    const float* o_w        = (const float*)d_in[4];
    const float* o_b        = (const float*)d_in[5];
    const float* bias_table = (const float*)d_in[6];
    const int*   rel_index  = (const int*)d_in[7];

    char* ws = (char*)d_ws;
    _Float16* qkv      = (_Float16*)(ws + WS_QKV);
    _Float16* ao       = (_Float16*)(ws + WS_AO);
    _Float16* wqh      = (_Float16*)(ws + WS_AO);   // alias: consumed by K1 before K2 writes ao
    _Float16* w2       = (_Float16*)(ws + WS_W2);
    float*    bias_pre = (float*)(ws + WS_BIAS);
    float*    out      = (float*)d_out;
    _Float16* xh       = (_Float16*)d_out;          // scratch: K0 writes, K1 reads, K3 overwrites

    // K0: prep + bulk x->f16 (231 MB streamed)
    wa_k0_prep<<<2048, 256, 0, stream>>>(
        x, o_w, qkv_w, bias_table, rel_index, w2, wqh, bias_pre, xh);
    // K1: QKV GEMM, 128x64 tiles, async LDS staging, XCD-swizzled linear grid
    wa_k1_qkv<<<14112, 256, 0, stream>>>(xh, wqh, qkv_b, qkv);
    // K2: attention
    wa_k2_attn<<<dim3(NH, NB), 448, 0, stream>>>(qkv, mask, bias_pre, ao);
    // K3: out projection, XCD-swizzled linear grid
    wa_k3_proj<<<9408, 256, 0, stream>>>(ao, w2, o_b, out);
}